// Round 14
// baseline (91.904 us; speedup 1.0000x reference)
//
#include <hip/hip_runtime.h>
#include <hip/hip_bf16.h>

#define B_ 8
#define S_ 2048
#define DM 1024
#define DK 64

typedef __attribute__((ext_vector_type(8))) short bf16x8;
typedef __attribute__((ext_vector_type(4))) float f32x4;
typedef __attribute__((ext_vector_type(4))) short short4_t;
typedef unsigned int u32;

__device__ __forceinline__ short bf16s(float f) {
    union { float f; unsigned u; } v; v.f = f;
    unsigned r = v.u + 0x7fffu + ((v.u >> 16) & 1u);   // RNE
    return (short)(r >> 16);
}

// ---------------------------------------------------------------------------
// Kernel 0: convert W (3 x [64][1024] f32) -> bf16 in ws. 96 blocks x 256.
// ---------------------------------------------------------------------------
__global__ __launch_bounds__(256) void convw_kernel(
    const float* __restrict__ Wq, const float* __restrict__ Wk,
    const float* __restrict__ Wv, short* __restrict__ wbf)
{
    const int i = (blockIdx.x * 256 + threadIdx.x) * 8;
    const float* src = (i < 65536) ? Wq : (i < 131072) ? Wk : Wv;
    const int off = i & 65535;
    float4 f0 = *(const float4*)(src + off);
    float4 f1 = *(const float4*)(src + off + 4);
    bf16x8 o;
    o[0]=bf16s(f0.x); o[1]=bf16s(f0.y); o[2]=bf16s(f0.z); o[3]=bf16s(f0.w);
    o[4]=bf16s(f1.x); o[5]=bf16s(f1.y); o[6]=bf16s(f1.z); o[7]=bf16s(f1.w);
    *(bf16x8*)(wbf + i) = o;
}

// ---------------------------------------------------------------------------
// Kernel 1: fused QKV projection — round-12 proven structure (reg-staged,
// NON-TEMPORAL x loads, cached W, XOR-swizzled LDS dbuf). (256,3) x 256 thr.
// ---------------------------------------------------------------------------
__global__ __launch_bounds__(256) void proj_kernel(
    const float* __restrict__ xq, const float* __restrict__ xk, const float* __restrict__ xv,
    const short* __restrict__ wbf,
    const float* __restrict__ bq, const float* __restrict__ bk, const float* __restrict__ bv,
    short* __restrict__ q_ws, short* __restrict__ k_ws, short* __restrict__ vt_ws)
{
    // xs: [2][64 rows][256 B f32] @ 0 (32 KB); wl: [2][64 n][128 B bf16] @ 32768 (16 KB)
    __shared__ __align__(16) char smem[49152];

    const int which = blockIdx.y;
    const float* x    = (which == 0) ? xq : (which == 1) ? xk : xv;
    const float* bias = (which == 0) ? bq : (which == 1) ? bk : bv;
    const short* wsrc = wbf + which * (DK * DM);

    const int tid = threadIdx.x;
    const int w   = tid >> 6;
    const int i   = tid & 63;
    const int lr  = i & 15;
    const int g   = i >> 4;
    const int row0 = blockIdx.x * 64;
    const int rot = (blockIdx.x * 5 + which * 7) & 15;

    f32x4 acc[4];
    #pragma unroll
    for (int f = 0; f < 4; ++f) acc[f] = f32x4{0.f, 0.f, 0.f, 0.f};

    auto fetch = [&](f32x4 (&xb)[4], f32x4 (&wb)[2], int kc) {
        const float* xrow = x + (long)(row0 + w * 16) * DM + kc;
        #pragma unroll
        for (int j = 0; j < 4; ++j) {
            const int rl = j * 4 + g;
            xb[j] = __builtin_nontemporal_load(
                (const f32x4*)((const char*)(xrow + (long)rl * DM) + (i & 15) * 16));
        }
        const short* wrow = wsrc + (long)(w * 16) * DM + kc;
        #pragma unroll
        for (int j = 0; j < 2; ++j) {
            const int nl = j * 8 + (i >> 3);
            wb[j] = *(const f32x4*)((const char*)(wrow + (long)nl * DM) + (i & 7) * 16);
        }
    };
    auto writeLDS = [&](const f32x4 (&xb)[4], const f32x4 (&wb)[2], int buf) {
        char* xd = smem + buf * 16384 + (w * 16) * 256;
        #pragma unroll
        for (int j = 0; j < 4; ++j) {
            const int rl = j * 4 + g;
            *(f32x4*)(xd + rl * 256 + (((i & 15) * 16) ^ ((rl & 7) << 5))) = xb[j];
        }
        char* wd = smem + 32768 + buf * 8192 + (w * 16) * 128;
        #pragma unroll
        for (int j = 0; j < 2; ++j) {
            const int nl = j * 8 + (i >> 3);
            *(f32x4*)(wd + nl * 128 + (((i & 7) * 16) ^ ((nl & 7) << 4))) = wb[j];
        }
    };
    auto compute = [&](int buf) {
        const char* xr = smem + buf * 16384 + (w * 16 + lr) * 256;
        const char* wr = smem + 32768 + buf * 8192;
        const int sx = (lr & 7) << 5;
        const int sw = (lr & 7) << 4;
        #pragma unroll
        for (int ks = 0; ks < 2; ++ks) {
            const int bA = (ks * 128 + g * 32) ^ sx;
            f32x4 x0 = *(const f32x4*)(xr + bA);
            f32x4 x1 = *(const f32x4*)(xr + bA + 16);
            bf16x8 af;
            af[0]=bf16s(x0[0]); af[1]=bf16s(x0[1]); af[2]=bf16s(x0[2]); af[3]=bf16s(x0[3]);
            af[4]=bf16s(x1[0]); af[5]=bf16s(x1[1]); af[6]=bf16s(x1[2]); af[7]=bf16s(x1[3]);
            const int bB = (ks * 64 + g * 16) ^ sw;
            #pragma unroll
            for (int f = 0; f < 4; ++f) {
                bf16x8 wf = *(const bf16x8*)(wr + (f * 16 + lr) * 128 + bB);
                acc[f] = __builtin_amdgcn_mfma_f32_16x16x32_bf16(af, wf, acc[f], 0, 0, 0);
            }
        }
    };

    f32x4 xA[4], wA[2], xB[4], wB[2];
    fetch(xA, wA, rot * 64);
    writeLDS(xA, wA, 0);
    fetch(xB, wB, ((1 + rot) & 15) * 64);
    asm volatile("s_waitcnt lgkmcnt(0)" ::: "memory");
    asm volatile("s_barrier" ::: "memory");

    for (int t = 0; t < 16; t += 2) {
        compute(0);
        if (t + 2 < 16) fetch(xA, wA, ((t + 2 + rot) & 15) * 64);
        writeLDS(xB, wB, 1);
        asm volatile("s_waitcnt lgkmcnt(0)" ::: "memory");
        asm volatile("s_barrier" ::: "memory");
        compute(1);
        if (t + 3 < 16) fetch(xB, wB, ((t + 3 + rot) & 15) * 64);
        if (t + 2 < 16) {
            writeLDS(xA, wA, 0);
            asm volatile("s_waitcnt lgkmcnt(0)" ::: "memory");
        }
        asm volatile("s_barrier" ::: "memory");
    }

    if (which < 2) {
        short* stile = (short*)smem + w * 1024;
        #pragma unroll
        for (int f = 0; f < 4; ++f) {
            float bb = bias[f * 16 + lr];
            #pragma unroll
            for (int r = 0; r < 4; ++r)
                stile[(g * 4 + r) * 64 + f * 16 + lr] = bf16s(acc[f][r] + bb);
        }
        asm volatile("s_waitcnt lgkmcnt(0)" ::: "memory");
        __builtin_amdgcn_sched_barrier(0);
        short* outp = (which == 0) ? q_ws : k_ws;
        const long gbase = (long)(row0 + w * 16) * 64;
        *(bf16x8*)(outp + gbase +       i * 8) = *(const bf16x8*)(&stile[i * 8]);
        *(bf16x8*)(outp + gbase + 512 + i * 8) = *(const bf16x8*)(&stile[512 + i * 8]);
    } else {
        const int rw = row0 + w * 16;
        const int b = rw >> 11;
        const int s = (rw & 2047) + g * 4;
        #pragma unroll
        for (int f = 0; f < 4; ++f) {
            float bb = bias[f * 16 + lr];
            short4_t st;
            st[0]=bf16s(acc[f][0]+bb); st[1]=bf16s(acc[f][1]+bb);
            st[2]=bf16s(acc[f][2]+bb); st[3]=bf16s(acc[f][3]+bb);
            *(short4_t*)(vt_ws + (long)(b * 64 + f * 16 + lr) * S_ + s) = st;
        }
    }
}

// ---------------------------------------------------------------------------
// Kernel 2: causal flash attention, SOFTWARE-PIPELINED: K/V for iteration
// t+4 loaded into a 2nd register bank before computing iteration t, so the
// loads overlap the whole current iteration (QK, softmax, P-LDS, PV) despite
// the sched_barrier fence. 4-wave KV round-robin + LDS merge (round-10).
// ---------------------------------------------------------------------------
__global__ __launch_bounds__(256) void attn_kernel(
    const short* __restrict__ q_ws, const short* __restrict__ k_ws,
    const short* __restrict__ vt_ws, float* __restrict__ out)
{
    __shared__ __align__(16) short plds[4][16 * 40];
    __shared__ __align__(16) float accds[4][64][16];
    __shared__ __align__(16) float2 mlds[4][16];

    const int n = blockIdx.x;
    const int c = n & 255, s = n >> 8;
    const int u = c & 127, v = c >> 7;
    const int b  = v * 4 + s;
    const int qt = (s & 1) ? (127 - u) : u;
    const int qbase = qt * 16;
    const int kend  = qbase + 16;
    const int niter = (kend + 31) >> 5;

    const int tid  = threadIdx.x;
    const int wv   = tid >> 6;
    const int lane = tid & 63;
    const int lr = lane & 15, g = lane >> 4, lk = g * 8;
    const int q_glob = qbase + lr;

    const short* qp = q_ws + ((long)b * S_ + qbase + lr) * DK;
    const bf16x8 qb0 = *(const bf16x8*)(qp + lk);
    const bf16x8 qb1 = *(const bf16x8*)(qp + 32 + lk);
    const short* kb = k_ws  + (long)b * S_ * DK;
    const short* vb = vt_ws + (long)b * DK * S_;

    float m = -INFINITY, l = 0.f;
    f32x4 acc[4];
    #pragma unroll
    for (int f = 0; f < 4; ++f) acc[f] = f32x4{0.f, 0.f, 0.f, 0.f};
    const float sc = 0.125f * 1.44269504088896340736f;

    short* pw = plds[wv];

    // kf[0..1]: K subtile0 (k-halves); kf[2..3]: K subtile1 (clamped if absent)
    auto loadKV = [&](bf16x8 (&kf)[4], bf16x8 (&vf)[4], int t2) {
        const int kv = t2 * 32;
        const bool sub1 = (kv + 16) < kend;
        vf[0] = *(const bf16x8*)(vb + (long)(lr)      * S_ + kv + lk);
        vf[1] = *(const bf16x8*)(vb + (long)(16 + lr) * S_ + kv + lk);
        vf[2] = *(const bf16x8*)(vb + (long)(32 + lr) * S_ + kv + lk);
        vf[3] = *(const bf16x8*)(vb + (long)(48 + lr) * S_ + kv + lk);
        const short* kp0 = kb + (long)(kv + lr) * DK;
        kf[0] = *(const bf16x8*)(kp0 + lk);
        kf[1] = *(const bf16x8*)(kp0 + 32 + lk);
        const short* kp1 = kp0 + (sub1 ? 16 * DK : 0);
        kf[2] = *(const bf16x8*)(kp1 + lk);
        kf[3] = *(const bf16x8*)(kp1 + 32 + lk);
    };

    auto computeIter = [&](const bf16x8 (&kf)[4], const bf16x8 (&vf)[4], int t2) {
        const int kv = t2 * 32;
        const bool sub1 = (kv + 16) < kend;
        f32x4 s0 = f32x4{0.f,0.f,0.f,0.f};
        s0 = __builtin_amdgcn_mfma_f32_16x16x32_bf16(kf[0], qb0, s0, 0, 0, 0);
        s0 = __builtin_amdgcn_mfma_f32_16x16x32_bf16(kf[1], qb1, s0, 0, 0, 0);
        f32x4 s1 = f32x4{0.f,0.f,0.f,0.f};
        if (sub1) {
            s1 = __builtin_amdgcn_mfma_f32_16x16x32_bf16(kf[2], qb0, s1, 0, 0, 0);
            s1 = __builtin_amdgcn_mfma_f32_16x16x32_bf16(kf[3], qb1, s1, 0, 0, 0);
        }
        float pv[8];
        #pragma unroll
        for (int r = 0; r < 4; ++r) {
            const int key0 = kv + g*4 + r;
            pv[r]     = (key0 <= q_glob) ? s0[r] * sc : -INFINITY;
            const int key1 = kv + 16 + g*4 + r;
            pv[4 + r] = (sub1 && key1 <= q_glob) ? s1[r] * sc : -INFINITY;
        }
        float tm = fmaxf(fmaxf(fmaxf(pv[0],pv[1]), fmaxf(pv[2],pv[3])),
                         fmaxf(fmaxf(pv[4],pv[5]), fmaxf(pv[6],pv[7])));
        tm = fmaxf(tm, __shfl_xor(tm, 16));
        tm = fmaxf(tm, __shfl_xor(tm, 32));
        const float mn  = fmaxf(m, tm);
        const float fac = exp2f(m - mn);
        float ps = 0.f;
        #pragma unroll
        for (int q = 0; q < 8; ++q) { pv[q] = exp2f(pv[q] - mn); ps += pv[q]; }
        ps += __shfl_xor(ps, 16);
        ps += __shfl_xor(ps, 32);
        l = l * fac + ps;
        m = mn;
        #pragma unroll
        for (int f = 0; f < 4; ++f)
            #pragma unroll
            for (int r = 0; r < 4; ++r) acc[f][r] *= fac;

        short4_t pw0, pw1;
        pw0[0]=bf16s(pv[0]); pw0[1]=bf16s(pv[1]); pw0[2]=bf16s(pv[2]); pw0[3]=bf16s(pv[3]);
        pw1[0]=bf16s(pv[4]); pw1[1]=bf16s(pv[5]); pw1[2]=bf16s(pv[6]); pw1[3]=bf16s(pv[7]);
        *(short4_t*)(pw + lr*40 + g*4)      = pw0;
        *(short4_t*)(pw + lr*40 + 16 + g*4) = pw1;
        asm volatile("s_waitcnt lgkmcnt(0)" ::: "memory");
        __builtin_amdgcn_sched_barrier(0);
        const bf16x8 pf = *(const bf16x8*)(pw + lr*40 + lk);

        acc[0] = __builtin_amdgcn_mfma_f32_16x16x32_bf16(vf[0], pf, acc[0], 0, 0, 0);
        acc[1] = __builtin_amdgcn_mfma_f32_16x16x32_bf16(vf[1], pf, acc[1], 0, 0, 0);
        acc[2] = __builtin_amdgcn_mfma_f32_16x16x32_bf16(vf[2], pf, acc[2], 0, 0, 0);
        acc[3] = __builtin_amdgcn_mfma_f32_16x16x32_bf16(vf[3], pf, acc[3], 0, 0, 0);
    };

    // ---- software-pipelined loop: banks A/B, next loads issued before compute
    bf16x8 kA[4], vA[4], kB[4], vB[4];
    int t = wv;
    if (t < niter) loadKV(kA, vA, t);
    while (t < niter) {
        if (t + 4 < niter) loadKV(kB, vB, t + 4);
        computeIter(kA, vA, t);
        t += 4;
        if (t >= niter) break;
        if (t + 4 < niter) loadKV(kA, vA, t + 4);
        computeIter(kB, vB, t);
        t += 4;
    }

    // ---- cross-wave merge in LDS ----
    #pragma unroll
    for (int f = 0; f < 4; ++f)
        *(f32x4*)(&accds[wv][lane][f * 4]) = acc[f];
    if (g == 0) mlds[wv][lr] = float2{m, l};
    __syncthreads();

    const float2 ml0 = mlds[0][lr], ml1 = mlds[1][lr],
                 ml2 = mlds[2][lr], ml3 = mlds[3][lr];
    const float M = fmaxf(fmaxf(ml0.x, ml1.x), fmaxf(ml2.x, ml3.x));
    const float w0 = exp2f(ml0.x - M), w1 = exp2f(ml1.x - M),
                w2 = exp2f(ml2.x - M), w3 = exp2f(ml3.x - M);
    const float L = w0*ml0.y + w1*ml1.y + w2*ml2.y + w3*ml3.y;
    f32x4 o = w0 * (*(const f32x4*)(&accds[0][lane][wv * 4]))
            + w1 * (*(const f32x4*)(&accds[1][lane][wv * 4]))
            + w2 * (*(const f32x4*)(&accds[2][lane][wv * 4]))
            + w3 * (*(const f32x4*)(&accds[3][lane][wv * 4]));
    const float inv = 1.0f / L;
    o[0]*=inv; o[1]*=inv; o[2]*=inv; o[3]*=inv;
    *(f32x4*)(out + ((long)b * S_ + qbase + lr) * DK + wv * 16 + g * 4) = o;
}

extern "C" void kernel_launch(void* const* d_in, const int* in_sizes, int n_in,
                              void* d_out, int out_size, void* d_ws, size_t ws_size,
                              hipStream_t stream) {
    const float* q_in = (const float*)d_in[0];
    const float* k_in = (const float*)d_in[1];
    const float* v_in = (const float*)d_in[2];
    const float* Wq   = (const float*)d_in[3];
    const float* bq   = (const float*)d_in[4];
    const float* Wk   = (const float*)d_in[5];
    const float* bk   = (const float*)d_in[6];
    const float* Wv   = (const float*)d_in[7];
    const float* bv   = (const float*)d_in[8];

    short* q_ws  = (short*)d_ws;
    short* k_ws  = q_ws + (size_t)B_ * S_ * DK;
    short* vt_ws = k_ws + (size_t)B_ * S_ * DK;
    short* wbf   = vt_ws + (size_t)B_ * S_ * DK;
    float* out   = (float*)d_out;

    convw_kernel<<<dim3(96), 256, 0, stream>>>(Wq, Wk, Wv, wbf);
    proj_kernel<<<dim3((B_ * S_) / 64, 3), 256, 0, stream>>>(
        q_in, k_in, v_in, wbf, bq, bk, bv, q_ws, k_ws, vt_ws);
    attn_kernel<<<dim3(B_ * 128), 256, 0, stream>>>(q_ws, k_ws, vt_ws, out);
}

// Round 15
// 72.240 us; speedup vs baseline: 1.2722x; 1.2722x over previous
//
#include <hip/hip_runtime.h>
#include <hip/hip_bf16.h>

#define B_ 8
#define S_ 2048
#define DM 1024
#define DK 64

typedef __attribute__((ext_vector_type(8))) short bf16x8;
typedef __attribute__((ext_vector_type(4))) float f32x4;
typedef __attribute__((ext_vector_type(4))) short short4_t;
typedef unsigned int u32;

__device__ __forceinline__ short bf16s(float f) {
    union { float f; unsigned u; } v; v.f = f;
    unsigned r = v.u + 0x7fffu + ((v.u >> 16) & 1u);   // RNE
    return (short)(r >> 16);
}

__device__ __forceinline__ void gl_lds16(const void* g, void* l) {
    __builtin_amdgcn_global_load_lds(
        (const __attribute__((address_space(1))) u32*)g,
        (__attribute__((address_space(3))) u32*)l, 16, 0, 0);
}

// ---------------------------------------------------------------------------
// Kernel 0: convert W (3 x [64][1024] f32) -> bf16 in ws. 96 blocks x 256.
// ---------------------------------------------------------------------------
__global__ __launch_bounds__(256) void convw_kernel(
    const float* __restrict__ Wq, const float* __restrict__ Wk,
    const float* __restrict__ Wv, short* __restrict__ wbf)
{
    const int i = (blockIdx.x * 256 + threadIdx.x) * 8;
    const float* src = (i < 65536) ? Wq : (i < 131072) ? Wk : Wv;
    const int off = i & 65535;
    float4 f0 = *(const float4*)(src + off);
    float4 f1 = *(const float4*)(src + off + 4);
    bf16x8 o;
    o[0]=bf16s(f0.x); o[1]=bf16s(f0.y); o[2]=bf16s(f0.z); o[3]=bf16s(f0.w);
    o[4]=bf16s(f1.x); o[5]=bf16s(f1.y); o[6]=bf16s(f1.z); o[7]=bf16s(f1.w);
    *(bf16x8*)(wbf + i) = o;
}

// ---------------------------------------------------------------------------
// Kernel 1: fused QKV projection — R10's timed-best structure, verbatim:
// gl_lds staging (CACHED: wins when inputs are L3-resident in the timed
// loop), counted vmcnt(6) + raw s_barrier, XOR-swizzled via source.
// ---------------------------------------------------------------------------
__global__ __launch_bounds__(256) void proj_kernel(
    const float* __restrict__ xq, const float* __restrict__ xk, const float* __restrict__ xv,
    const short* __restrict__ wbf,
    const float* __restrict__ bq, const float* __restrict__ bk, const float* __restrict__ bv,
    short* __restrict__ q_ws, short* __restrict__ k_ws, short* __restrict__ vt_ws)
{
    __shared__ __align__(16) char smem[49152];

    const int which = blockIdx.y;
    const float* x    = (which == 0) ? xq : (which == 1) ? xk : xv;
    const float* bias = (which == 0) ? bq : (which == 1) ? bk : bv;
    const short* wsrc = wbf + which * (DK * DM);

    const int tid = threadIdx.x;
    const int w   = tid >> 6;
    const int i   = tid & 63;
    const int lr  = i & 15;
    const int g   = i >> 4;
    const int row0 = blockIdx.x * 64;

    const int rot = (blockIdx.x * 5 + which * 7) & 15;

    f32x4 acc[4];
    #pragma unroll
    for (int f = 0; f < 4; ++f) acc[f] = f32x4{0.f, 0.f, 0.f, 0.f};

    auto stage = [&](int buf, int kc) {
        char* xd = smem + buf * 16384 + (w * 16) * 256;
        const float* xrow = x + (long)(row0 + w * 16) * DM + kc;
        #pragma unroll
        for (int j = 0; j < 4; ++j) {
            const int rl  = j * 4 + (i >> 4);
            const int byt = ((i & 15) * 16) ^ ((rl & 7) << 5);
            gl_lds16((const char*)(xrow + (long)rl * DM) + byt, xd + j * 1024);
        }
        char* wd = smem + 32768 + buf * 8192 + (w * 16) * 128;
        const short* wrow = wsrc + (long)(w * 16) * DM + kc;
        #pragma unroll
        for (int j = 0; j < 2; ++j) {
            const int nl  = j * 8 + (i >> 3);
            const int byt = ((i & 7) * 16) ^ ((nl & 7) << 4);
            gl_lds16((const char*)(wrow + (long)nl * DM) + byt, wd + j * 1024);
        }
    };

    auto compute = [&](int buf) {
        const char* xr = smem + buf * 16384 + (w * 16 + lr) * 256;
        const char* wr = smem + 32768 + buf * 8192;
        const int sx = (lr & 7) << 5;
        const int sw = (lr & 7) << 4;
        #pragma unroll
        for (int ks = 0; ks < 2; ++ks) {
            const int bA = (ks * 128 + g * 32) ^ sx;
            f32x4 x0 = *(const f32x4*)(xr + bA);
            f32x4 x1 = *(const f32x4*)(xr + bA + 16);
            bf16x8 af;
            af[0]=bf16s(x0[0]); af[1]=bf16s(x0[1]); af[2]=bf16s(x0[2]); af[3]=bf16s(x0[3]);
            af[4]=bf16s(x1[0]); af[5]=bf16s(x1[1]); af[6]=bf16s(x1[2]); af[7]=bf16s(x1[3]);
            const int bB = (ks * 64 + g * 16) ^ sw;
            #pragma unroll
            for (int f = 0; f < 4; ++f) {
                bf16x8 wf = *(const bf16x8*)(wr + (f * 16 + lr) * 128 + bB);
                acc[f] = __builtin_amdgcn_mfma_f32_16x16x32_bf16(af, wf, acc[f], 0, 0, 0);
            }
        }
    };

    stage(0, rot * 64);
    __builtin_amdgcn_sched_barrier(0);
    stage(1, ((1 + rot) & 15) * 64);
    __builtin_amdgcn_sched_barrier(0);

    #pragma unroll 2
    for (int t = 0; t < 16; ++t) {
        if (t < 15) asm volatile("s_waitcnt vmcnt(6)" ::: "memory");
        else        asm volatile("s_waitcnt vmcnt(0)" ::: "memory");
        asm volatile("s_barrier" ::: "memory");
        const int buf = t & 1;
        compute(buf);
        asm volatile("s_waitcnt lgkmcnt(0)" ::: "memory");
        asm volatile("s_barrier" ::: "memory");
        if (t + 2 < 16) stage(buf, ((t + 2 + rot) & 15) * 64);
    }

    if (which < 2) {
        short* stile = (short*)smem + w * 1024;
        #pragma unroll
        for (int f = 0; f < 4; ++f) {
            float bb = bias[f * 16 + lr];
            #pragma unroll
            for (int r = 0; r < 4; ++r)
                stile[(g * 4 + r) * 64 + f * 16 + lr] = bf16s(acc[f][r] + bb);
        }
        asm volatile("s_waitcnt lgkmcnt(0)" ::: "memory");
        __builtin_amdgcn_sched_barrier(0);
        short* outp = (which == 0) ? q_ws : k_ws;
        const long gbase = (long)(row0 + w * 16) * 64;
        *(bf16x8*)(outp + gbase +       i * 8) = *(const bf16x8*)(&stile[i * 8]);
        *(bf16x8*)(outp + gbase + 512 + i * 8) = *(const bf16x8*)(&stile[512 + i * 8]);
    } else {
        const int rw = row0 + w * 16;
        const int b = rw >> 11;
        const int s = (rw & 2047) + g * 4;
        #pragma unroll
        for (int f = 0; f < 4; ++f) {
            float bb = bias[f * 16 + lr];
            short4_t st;
            st[0]=bf16s(acc[f][0]+bb); st[1]=bf16s(acc[f][1]+bb);
            st[2]=bf16s(acc[f][2]+bb); st[3]=bf16s(acc[f][3]+bb);
            *(short4_t*)(vt_ws + (long)(b * 64 + f * 16 + lr) * S_ + s) = st;
        }
    }
}

// ---------------------------------------------------------------------------
// Kernel 2: causal flash attention — REGISTER-RESIDENT P. K A-fragment rows
// are permuted (frag row m <- key (m>>2)*8+(m&3), +4 for MFMA-1) so lane
// (lr,g) holds keys kv+g*8..+7 contiguous: P is directly the PV B-fragment.
// No LDS P-transpose, no per-iter fences; sum-reduction deferred to loop end.
// 4-wave KV round-robin + LDS merge + CU-aware mapping (R10 proven frame).
// ---------------------------------------------------------------------------
__global__ __launch_bounds__(256) void attn_kernel(
    const short* __restrict__ q_ws, const short* __restrict__ k_ws,
    const short* __restrict__ vt_ws, float* __restrict__ out)
{
    __shared__ __align__(16) float accds[4][64][16];
    __shared__ __align__(16) float2 mlds[4][16];

    const int n = blockIdx.x;
    const int c = n & 255, s = n >> 8;
    const int u = c & 127, v = c >> 7;
    const int b  = v * 4 + s;
    const int qt = (s & 1) ? (127 - u) : u;
    const int qbase = qt * 16;
    const int kend  = qbase + 16;
    const int niter = (kend + 31) >> 5;

    const int tid  = threadIdx.x;
    const int wv   = tid >> 6;
    const int lane = tid & 63;
    const int lr = lane & 15, g = lane >> 4, lk = g * 8;
    const int q_glob = qbase + lr;

    const short* qp = q_ws + ((long)b * S_ + qbase + lr) * DK;
    const bf16x8 qb0 = *(const bf16x8*)(qp + lk);
    const bf16x8 qb1 = *(const bf16x8*)(qp + 32 + lk);
    // permuted K row for A-frag row m=lr (keys kperm, kperm+4 always < S_)
    const int kperm = ((lr >> 2) << 3) + (lr & 3);
    const short* kb = k_ws  + (long)b * S_ * DK;
    const short* vb = vt_ws + (long)b * DK * S_;

    float m = -INFINITY, l = 0.f;
    f32x4 acc[4];
    #pragma unroll
    for (int f = 0; f < 4; ++f) acc[f] = f32x4{0.f, 0.f, 0.f, 0.f};
    const float sc = 0.125f * 1.44269504088896340736f;   // 1/sqrt(64)*log2(e)

    for (int t = wv; t < niter; t += 4) {
        const int kv = t * 32;
        // V^T A-frags: V^T[dv=f*16+lr][keys kv+g*8..+7]
        bf16x8 vf0 = *(const bf16x8*)(vb + (long)(lr)      * S_ + kv + lk);
        bf16x8 vf1 = *(const bf16x8*)(vb + (long)(16 + lr) * S_ + kv + lk);
        bf16x8 vf2 = *(const bf16x8*)(vb + (long)(32 + lr) * S_ + kv + lk);
        bf16x8 vf3 = *(const bf16x8*)(vb + (long)(48 + lr) * S_ + kv + lk);

        // K A-frags, permuted rows (max row kv+31 <= 2047: always in-bounds;
        // causal mask zeroes any key beyond q_glob)
        const short* kp0 = kb + (long)(kv + kperm) * DK;
        const short* kp1 = kp0 + 4 * DK;
        bf16x8 k00 = *(const bf16x8*)(kp0 + lk);
        bf16x8 k01 = *(const bf16x8*)(kp0 + 32 + lk);
        bf16x8 k10 = *(const bf16x8*)(kp1 + lk);
        bf16x8 k11 = *(const bf16x8*)(kp1 + 32 + lk);

        f32x4 s0 = f32x4{0.f,0.f,0.f,0.f};
        s0 = __builtin_amdgcn_mfma_f32_16x16x32_bf16(k00, qb0, s0, 0, 0, 0);
        s0 = __builtin_amdgcn_mfma_f32_16x16x32_bf16(k01, qb1, s0, 0, 0, 0);
        f32x4 s1 = f32x4{0.f,0.f,0.f,0.f};
        s1 = __builtin_amdgcn_mfma_f32_16x16x32_bf16(k10, qb0, s1, 0, 0, 0);
        s1 = __builtin_amdgcn_mfma_f32_16x16x32_bf16(k11, qb1, s1, 0, 0, 0);

        // lane (lr,g) holds keys kv+g*8+j, j=0..7: pv[j] lane-local full q-row slice
        float pv[8];
        #pragma unroll
        for (int r = 0; r < 4; ++r) {
            const int key0 = kv + g * 8 + r;
            pv[r]     = (key0 <= q_glob) ? s0[r] * sc : -INFINITY;
            const int key1 = kv + g * 8 + 4 + r;
            pv[4 + r] = (key1 <= q_glob) ? s1[r] * sc : -INFINITY;
        }
        float tm = fmaxf(fmaxf(fmaxf(pv[0],pv[1]), fmaxf(pv[2],pv[3])),
                         fmaxf(fmaxf(pv[4],pv[5]), fmaxf(pv[6],pv[7])));
        tm = fmaxf(tm, __shfl_xor(tm, 16));
        tm = fmaxf(tm, __shfl_xor(tm, 32));
        const float mn  = fmaxf(m, tm);
        const float fac = exp2f(m - mn);
        float ps = 0.f;
        #pragma unroll
        for (int q = 0; q < 8; ++q) { pv[q] = exp2f(pv[q] - mn); ps += pv[q]; }
        l = l * fac + ps;      // lane-partial sum; row-reduced once after loop
        m = mn;
        #pragma unroll
        for (int f = 0; f < 4; ++f)
            #pragma unroll
            for (int r = 0; r < 4; ++r) acc[f][r] *= fac;

        // P -> bf16 in registers: directly the PV B-fragment (k=g*8+j, n=lr)
        bf16x8 pf;
        #pragma unroll
        for (int q = 0; q < 8; ++q) pf[q] = bf16s(pv[q]);

        acc[0] = __builtin_amdgcn_mfma_f32_16x16x32_bf16(vf0, pf, acc[0], 0, 0, 0);
        acc[1] = __builtin_amdgcn_mfma_f32_16x16x32_bf16(vf1, pf, acc[1], 0, 0, 0);
        acc[2] = __builtin_amdgcn_mfma_f32_16x16x32_bf16(vf2, pf, acc[2], 0, 0, 0);
        acc[3] = __builtin_amdgcn_mfma_f32_16x16x32_bf16(vf3, pf, acc[3], 0, 0, 0);
    }

    // deferred row-sum of l across the 4 lane-groups (m already row-consistent)
    l += __shfl_xor(l, 16);
    l += __shfl_xor(l, 32);

    // ---- cross-wave merge in LDS ----
    #pragma unroll
    for (int f = 0; f < 4; ++f)
        *(f32x4*)(&accds[wv][lane][f * 4]) = acc[f];
    if (g == 0) mlds[wv][lr] = float2{m, l};
    __syncthreads();

    const float2 ml0 = mlds[0][lr], ml1 = mlds[1][lr],
                 ml2 = mlds[2][lr], ml3 = mlds[3][lr];
    const float M = fmaxf(fmaxf(ml0.x, ml1.x), fmaxf(ml2.x, ml3.x));
    const float w0 = exp2f(ml0.x - M), w1 = exp2f(ml1.x - M),
                w2 = exp2f(ml2.x - M), w3 = exp2f(ml3.x - M);
    const float L = w0*ml0.y + w1*ml1.y + w2*ml2.y + w3*ml3.y;
    f32x4 o = w0 * (*(const f32x4*)(&accds[0][lane][wv * 4]))
            + w1 * (*(const f32x4*)(&accds[1][lane][wv * 4]))
            + w2 * (*(const f32x4*)(&accds[2][lane][wv * 4]))
            + w3 * (*(const f32x4*)(&accds[3][lane][wv * 4]));
    const float inv = 1.0f / L;
    o[0]*=inv; o[1]*=inv; o[2]*=inv; o[3]*=inv;
    *(f32x4*)(out + ((long)b * S_ + qbase + lr) * DK + wv * 16 + g * 4) = o;
}

extern "C" void kernel_launch(void* const* d_in, const int* in_sizes, int n_in,
                              void* d_out, int out_size, void* d_ws, size_t ws_size,
                              hipStream_t stream) {
    const float* q_in = (const float*)d_in[0];
    const float* k_in = (const float*)d_in[1];
    const float* v_in = (const float*)d_in[2];
    const float* Wq   = (const float*)d_in[3];
    const float* bq   = (const float*)d_in[4];
    const float* Wk   = (const float*)d_in[5];
    const float* bk   = (const float*)d_in[6];
    const float* Wv   = (const float*)d_in[7];
    const float* bv   = (const float*)d_in[8];

    short* q_ws  = (short*)d_ws;
    short* k_ws  = q_ws + (size_t)B_ * S_ * DK;
    short* vt_ws = k_ws + (size_t)B_ * S_ * DK;
    short* wbf   = vt_ws + (size_t)B_ * S_ * DK;
    float* out   = (float*)d_out;

    convw_kernel<<<dim3(96), 256, 0, stream>>>(Wq, Wk, Wv, wbf);
    proj_kernel<<<dim3((B_ * S_) / 64, 3), 256, 0, stream>>>(
        q_in, k_in, v_in, wbf, bq, bk, bv, q_ws, k_ws, vt_ws);
    attn_kernel<<<dim3(B_ * 128), 256, 0, stream>>>(q_ws, k_ws, vt_ws, out);
}